// Round 2
// baseline (287.950 us; speedup 1.0000x reference)
//
#include <hip/hip_runtime.h>
#include <hip/hip_bf16.h>

// B=2, T=2048, C=1024, H=16, Dh=64
// ws layout (bytes):
//   xb   [4096x1024] bf16 @ 0          (8 MB)  -- dead after qkv GEMM
//   wat  [3072x1024] bf16 @ 8388608    (6 MB)  -- dead after qkv GEMM
//   (xb+wat+pad = [0,16777216) reused as oacc fp32 [4096][1024] during attn)
//   qk   [4096x2048] bf16 @ 16777216   (16 MB; Q cols pre-scaled by (1/8)log2e)
//   wpt  [1024x1024] bf16 @ 33554432   (2 MB)
//   vt   [2][16][64][2048] bf16 @ 35651584 (8 MB) -- reused as yb after attn
// dacc fp32 [4096][16] lives in d_out (scratch until proj writes it).

typedef __attribute__((ext_vector_type(8))) __bf16 bf16x8;
typedef __attribute__((ext_vector_type(4))) float  floatx4;
typedef __attribute__((ext_vector_type(4))) float  fvec4;
typedef __attribute__((ext_vector_type(4))) short  short4v;

#define MFMA16(a, b, c) __builtin_amdgcn_mfma_f32_16x16x32_bf16(a, b, c, 0, 0, 0)

using as1v = const __attribute__((address_space(1))) void;
using as3v = __attribute__((address_space(3))) void;
__device__ __forceinline__ void async16(const void* g, void* l) {
  __builtin_amdgcn_global_load_lds((as1v*)g, (as3v*)l, 16, 0, 0);
}

__device__ inline void store_out(float* p, float v) { *p = v; }
__device__ inline void store_out(__hip_bfloat16* p, float v) { *p = __float2bfloat16(v); }

// ---------------- fused prep: cast x; 64x64 vectorized transpose+cast of weights ----------------
__global__ __launch_bounds__(256) void prep_kernel(const float* __restrict__ x,
                                                   const float* __restrict__ w_attn,
                                                   const float* __restrict__ w_proj,
                                                   __hip_bfloat16* __restrict__ xb,
                                                   __hip_bfloat16* __restrict__ wat,
                                                   __hip_bfloat16* __restrict__ wpt) {
  const int bid = blockIdx.x, tid = threadIdx.x;
  if (bid < 4096) {  // cast x -> bf16 (4 elems/thread)
    const int i = (bid * 256 + tid) * 4;
    fvec4 v = *(const fvec4*)(x + i);
    union { short4v s; __hip_bfloat16 h[4]; } u;
#pragma unroll
    for (int j = 0; j < 4; ++j) u.h[j] = __float2bfloat16(v[j]);
    *(short4v*)((short*)xb + i) = u.s;
    return;
  }
  __shared__ __align__(16) __hip_bfloat16 tile[64 * 64];
  const float* in;
  __hip_bfloat16* out;
  int cols, bx, by;
  if (bid < 4864) {
    const int b2 = bid - 4096;
    in = w_attn; out = wat; cols = 3072; bx = b2 % 48; by = b2 / 48;
  } else {
    const int b2 = bid - 4864;
    in = w_proj; out = wpt; cols = 1024; bx = b2 % 16; by = b2 / 16;
  }
  const int c0 = bx * 64, r0 = by * 64;  // input rows = 1024
#pragma unroll
  for (int it = 0; it < 2; ++it) {
    const int c = it * 256 + tid;
    const int row = c >> 3, cg = c & 7;
    const float* src = in + (long)(r0 + row) * cols + c0 + cg * 8;
    fvec4 v0 = *(const fvec4*)src;
    fvec4 v1 = *(const fvec4*)(src + 4);
    union { bf16x8 v; __hip_bfloat16 h[8]; } u;
#pragma unroll
    for (int j = 0; j < 4; ++j) { u.h[j] = __float2bfloat16(v0[j]); u.h[4 + j] = __float2bfloat16(v1[j]); }
    *(bf16x8*)(tile + row * 64 + (cg ^ ((row >> 3) & 7)) * 8) = u.v;
  }
  __syncthreads();
#pragma unroll
  for (int it = 0; it < 2; ++it) {
    const int c = it * 256 + tid;
    const int dr = c >> 3, tg = c & 7;
    union { bf16x8 v; __hip_bfloat16 e[8]; } u;
    const int pg = (dr >> 3) ^ tg;
#pragma unroll
    for (int j = 0; j < 8; ++j)
      u.e[j] = tile[(tg * 8 + j) * 64 + pg * 8 + (dr & 7)];
    *(bf16x8*)(out + (long)(c0 + dr) * 1024 + r0 + tg * 8) = u.v;
  }
}

// ------------- qkv GEMM: A[4096,1024] x wat^T -> qk[4096,2048] + vt (V transposed) -------------
__global__ __launch_bounds__(256) void gemm_qkv_kernel(const __hip_bfloat16* __restrict__ A,
                                                       const __hip_bfloat16* __restrict__ Bt,
                                                       __hip_bfloat16* __restrict__ qk,
                                                       __hip_bfloat16* __restrict__ vt,
                                                       float qscale) {
  const int K = 1024;
  __shared__ __align__(16) __hip_bfloat16 As[2][128 * 32];
  __shared__ __align__(16) __hip_bfloat16 Bs[2][128 * 32];
  const int tid = threadIdx.x;
  const int lane = tid & 63, wv = tid >> 6;
  const int l15 = lane & 15, quad = lane >> 4;
  const int wm = wv >> 1, wn = wv & 1;
  const long m0 = (long)blockIdx.y * 128, n0 = (long)blockIdx.x * 128;
  floatx4 acc[4][4] = {};
  const int nk = K >> 5;

  auto issue = [&](int kt, int p) {
    const int k0 = kt << 5;
#pragma unroll
    for (int it = 0; it < 2; ++it) {
      const int c = it * 256 + tid;
      const int row = c >> 2;
      const int lcg = (c & 3) ^ ((row >> 1) & 3);
      async16(A + (m0 + row) * K + k0 + lcg * 8, (char*)&As[p][0] + c * 16);
      async16(Bt + (n0 + row) * K + k0 + lcg * 8, (char*)&Bs[p][0] + c * 16);
    }
  };

  issue(0, 0);
  for (int kt = 0; kt < nk; ++kt) {
    const int p = kt & 1;
    __syncthreads();
    if (kt + 1 < nk) issue(kt + 1, p ^ 1);
    bf16x8 af[4], bfr[4];
#pragma unroll
    for (int t = 0; t < 4; ++t) {
      const int ar = wm * 64 + t * 16 + l15;
      const int br = wn * 64 + t * 16 + l15;
      af[t]  = *(const bf16x8*)(&As[p][ar * 32 + (quad ^ ((ar >> 1) & 3)) * 8]);
      bfr[t] = *(const bf16x8*)(&Bs[p][br * 32 + (quad ^ ((br >> 1) & 3)) * 8]);
    }
#pragma unroll
    for (int mt = 0; mt < 4; ++mt)
#pragma unroll
      for (int nt = 0; nt < 4; ++nt)
        acc[mt][nt] = MFMA16(af[mt], bfr[nt], acc[mt][nt]);
  }

#pragma unroll
  for (int nt = 0; nt < 4; ++nt) {
    const int colb = (int)n0 + wn * 64 + nt * 16;  // wave-uniform, multiple of 16
    if (colb >= 2048) {
      const int hh = (colb - 2048) >> 6;
      const int d  = (colb & 63) + l15;
#pragma unroll
      for (int mt = 0; mt < 4; ++mt) {
        const long row = m0 + wm * 64 + mt * 16 + quad * 4;
        const long b   = row >> 11;
        const long t0  = row & 2047;
        union { short4v s; __hip_bfloat16 h[4]; } uy;
#pragma unroll
        for (int r = 0; r < 4; ++r) uy.h[r] = __float2bfloat16(acc[mt][nt][r]);
        *(short4v*)(vt + ((b * 16 + hh) * 64 + d) * 2048 + t0) = uy.s;
      }
    } else {
      const float sc = (colb < 1024) ? qscale : 1.0f;
      const long col = colb + l15;
#pragma unroll
      for (int mt = 0; mt < 4; ++mt)
#pragma unroll
        for (int r = 0; r < 4; ++r) {
          const long row = m0 + wm * 64 + mt * 16 + quad * 4 + r;
          qk[row * 2048 + col] = __float2bfloat16(acc[mt][nt][r] * sc);
        }
    }
  }
}

// ------------- GEMM 128x64 (proj) -------------
template <typename OutT>
__global__ __launch_bounds__(256) void gemm_bt64_kernel(const __hip_bfloat16* __restrict__ A,
                                                        const __hip_bfloat16* __restrict__ Bt,
                                                        OutT* __restrict__ C,
                                                        int M, int N, int K) {
  __shared__ __align__(16) __hip_bfloat16 As[2][128 * 32];
  __shared__ __align__(16) __hip_bfloat16 Bs[2][64 * 32];
  const int tid = threadIdx.x;
  const int lane = tid & 63, wv = tid >> 6;
  const int l15 = lane & 15, quad = lane >> 4;
  const int wm = wv >> 1, wn = wv & 1;
  const long m0 = (long)blockIdx.y * 128, n0 = (long)blockIdx.x * 64;
  floatx4 acc[4][2] = {};
  const int nk = K >> 5;

  auto issue = [&](int kt, int p) {
    const int k0 = kt << 5;
#pragma unroll
    for (int it = 0; it < 2; ++it) {
      const int c = it * 256 + tid;
      const int row = c >> 2;
      const int lcg = (c & 3) ^ ((row >> 1) & 3);
      async16(A + (m0 + row) * K + k0 + lcg * 8, (char*)&As[p][0] + c * 16);
    }
    {
      const int c = tid;
      const int row = c >> 2;
      const int lcg = (c & 3) ^ ((row >> 1) & 3);
      async16(Bt + (n0 + row) * K + k0 + lcg * 8, (char*)&Bs[p][0] + c * 16);
    }
  };

  issue(0, 0);
  for (int kt = 0; kt < nk; ++kt) {
    const int p = kt & 1;
    __syncthreads();
    if (kt + 1 < nk) issue(kt + 1, p ^ 1);
    bf16x8 af[4], bfr[2];
#pragma unroll
    for (int t = 0; t < 4; ++t) {
      const int ar = wm * 64 + t * 16 + l15;
      af[t] = *(const bf16x8*)(&As[p][ar * 32 + (quad ^ ((ar >> 1) & 3)) * 8]);
    }
#pragma unroll
    for (int t = 0; t < 2; ++t) {
      const int br = wn * 32 + t * 16 + l15;
      bfr[t] = *(const bf16x8*)(&Bs[p][br * 32 + (quad ^ ((br >> 1) & 3)) * 8]);
    }
#pragma unroll
    for (int mt = 0; mt < 4; ++mt)
#pragma unroll
      for (int nt = 0; nt < 2; ++nt)
        acc[mt][nt] = MFMA16(af[mt], bfr[nt], acc[mt][nt]);
  }
#pragma unroll
  for (int mt = 0; mt < 4; ++mt)
#pragma unroll
    for (int nt = 0; nt < 2; ++nt)
#pragma unroll
      for (int r = 0; r < 4; ++r) {
        const long row = m0 + wm * 64 + mt * 16 + quad * 4 + r;
        const long col = n0 + wn * 32 + nt * 16 + l15;
        store_out(C + row * N + col, acc[mt][nt][r]);
      }
}

// ------------- paired-tile flash attention, k-parity split at BLOCK level -------------
// Round-0 proven 256-thread body; each (pair,h,b) now has TWO blocks, parity p handling
// k-tiles kt ≡ p (mod 2). Grid 1024 blocks -> 4 blocks/CU (LDS 40KB x4 = 160KiB exactly),
// 16 waves/CU (was 8). Partials merged via fp32 atomicAdd (2 commutative addends per
// address -> deterministic; valid since this softmax has no running max).
__global__ __launch_bounds__(256) void attn_kernel(const __hip_bfloat16* __restrict__ qk,
                                                   const __hip_bfloat16* __restrict__ vtg,
                                                   float* __restrict__ oacc,
                                                   float* __restrict__ dacc) {
  __shared__ __align__(16) __hip_bfloat16 Ks[2][64 * 64];
  __shared__ __align__(16) __hip_bfloat16 Vt[2][64 * 64];
  __shared__ __align__(16) __hip_bfloat16 Pb[4][16 * 64];  // per-wave P[q][k]
  const int tid = threadIdx.x;
  const int lane = tid & 63, wv = tid >> 6;
  const int l15 = lane & 15, quad = lane >> 4;
  const int pt = blockIdx.x >> 1, par = blockIdx.x & 1;
  const int h = blockIdx.y, b = blockIdx.z;
  const int qtA = pt, qtB = 31 - pt;
  const int q0A = qtA * 64, q0B = qtB * 64;
  const long bh = (long)b * 16 + h;
  const long RS = 2048;

  auto issue = [&](int kt, int p) {
    const int kb = kt * 64;
#pragma unroll
    for (int it = 0; it < 2; ++it) {
      const int c = it * 256 + tid;
      const int row = c >> 3;
      const int cg = (c & 7) ^ (row & 7);
      async16(qk + ((long)b * 2048 + kb + row) * RS + 1024 + h * 64 + cg * 8,
              (char*)&Ks[p][0] + c * 16);
      async16(vtg + (bh * 64 + row) * 2048 + kb + cg * 8, (char*)&Vt[p][0] + c * 16);
    }
  };

  bf16x8 bqA0, bqA1, bqB0, bqB1;
  {
    const __hip_bfloat16* qpA = qk + ((long)b * 2048 + q0A + wv * 16 + l15) * RS + h * 64 + quad * 8;
    bqA0 = *(const bf16x8*)qpA;
    bqA1 = *(const bf16x8*)(qpA + 32);
    const __hip_bfloat16* qpB = qk + ((long)b * 2048 + q0B + wv * 16 + l15) * RS + h * 64 + quad * 8;
    bqB0 = *(const bf16x8*)qpB;
    bqB1 = *(const bf16x8*)(qpB + 32);
  }
  union { bf16x8 v; __hip_bfloat16 e[8]; } uo;
#pragma unroll
  for (int j = 0; j < 8; ++j) uo.e[j] = __float2bfloat16(1.0f);
  const bf16x8 ones = uo.v;

  floatx4 oA[4] = {}, oB[4] = {}, o4A = {}, o4B = {};
  __hip_bfloat16* Pw = &Pb[wv][0];
  const int m7 = l15 & 7;

  issue(par, 0);
  int bufp = 0;
  for (int kt = par; kt <= qtB; kt += 2, bufp ^= 1) {
    const int kb = kt * 64;
    const bool actA = (kt <= qtA);
    __syncthreads();
    if (kt + 2 <= qtB) issue(kt + 2, bufp ^ 1);

    bf16x8 kf[4][2], vf[4][2];
#pragma unroll
    for (int nt = 0; nt < 4; ++nt) {
      const int row = nt * 16 + l15;
      const int s0 = (quad ^ (row & 7)) * 8, s1 = ((quad + 4) ^ (row & 7)) * 8;
      kf[nt][0] = *(const bf16x8*)(&Ks[bufp][row * 64 + s0]);
      kf[nt][1] = *(const bf16x8*)(&Ks[bufp][row * 64 + s1]);
      vf[nt][0] = *(const bf16x8*)(&Vt[bufp][row * 64 + s0]);
      vf[nt][1] = *(const bf16x8*)(&Vt[bufp][row * 64 + s1]);
    }

    auto tile = [&](const bf16x8& bq0, const bf16x8& bq1, floatx4* o, floatx4& o4,
                    bool diag, int q0X) {
      floatx4 st[4] = {};
#pragma unroll
      for (int nt = 0; nt < 4; ++nt) {
        st[nt] = MFMA16(kf[nt][0], bq0, st[nt]);
        st[nt] = MFMA16(kf[nt][1], bq1, st[nt]);
      }
      const int qg = q0X + wv * 16 + l15;
#pragma unroll
      for (int nt = 0; nt < 4; ++nt) {
        union { short4v s; __hip_bfloat16 h[4]; } up;
#pragma unroll
        for (int r = 0; r < 4; ++r) {
          float pv = exp2f(st[nt][r]);
          if (diag && (kb + nt * 16 + quad * 4 + r > qg)) pv = 0.f;
          up.h[r] = __float2bfloat16(pv);
        }
        const int chunk = (nt * 2 + (quad >> 1)) ^ m7;
        *(short4v*)(Pw + l15 * 64 + chunk * 8 + (quad & 1) * 4) = up.s;
      }
      const bf16x8 pb0 = *(const bf16x8*)(Pw + l15 * 64 + (quad ^ m7) * 8);
      const bf16x8 pb1 = *(const bf16x8*)(Pw + l15 * 64 + ((quad + 4) ^ m7) * 8);
#pragma unroll
      for (int mt = 0; mt < 4; ++mt) {
        o[mt] = MFMA16(vf[mt][0], pb0, o[mt]);
        o[mt] = MFMA16(vf[mt][1], pb1, o[mt]);
      }
      o4 = MFMA16(ones, pb0, o4);
      o4 = MFMA16(ones, pb1, o4);
    };

    tile(bqB0, bqB1, oB, o4B, kt == qtB, q0B);
    if (actA) tile(bqA0, bqA1, oA, o4A, kt == qtA, q0A);
  }

  auto epi = [&](floatx4* o, floatx4& o4, int q0X) {
    const long t = (long)b * 2048 + q0X + wv * 16 + l15;
    float* ob = oacc + t * 1024 + h * 64 + quad * 4;
#pragma unroll
    for (int mt = 0; mt < 4; ++mt)
#pragma unroll
      for (int r = 0; r < 4; ++r)
        atomicAdd(ob + mt * 16 + r, o[mt][r]);
    if (quad == 0) atomicAdd(dacc + t * 16 + h, o4[0]);
  };
  epi(oA, o4A, q0A);
  epi(oB, o4B, q0B);
}

// ------------- merge: y = oacc / dacc, cast bf16 -------------
__global__ __launch_bounds__(256) void merge_kernel(const float* __restrict__ oacc,
                                                    const float* __restrict__ dacc,
                                                    __hip_bfloat16* __restrict__ y) {
  const int i = (blockIdx.x * 256 + threadIdx.x) * 4;
  const int row = i >> 10, hh = (i >> 6) & 15;
  const float inv = 1.0f / dacc[row * 16 + hh];
  fvec4 v = *(const fvec4*)(oacc + i);
  union { short4v s; __hip_bfloat16 h[4]; } u;
#pragma unroll
  for (int j = 0; j < 4; ++j) u.h[j] = __float2bfloat16(v[j] * inv);
  *(short4v*)((short*)y + i) = u.s;
}

extern "C" void kernel_launch(void* const* d_in, const int* in_sizes, int n_in,
                              void* d_out, int out_size, void* d_ws, size_t ws_size,
                              hipStream_t stream) {
  const float* x      = (const float*)d_in[0];
  const float* w_attn = (const float*)d_in[1];
  const float* w_proj = (const float*)d_in[2];
  float* out = (float*)d_out;
  char* ws = (char*)d_ws;
  __hip_bfloat16* xb  = (__hip_bfloat16*)(ws);
  __hip_bfloat16* wat = (__hip_bfloat16*)(ws + 8388608);
  __hip_bfloat16* qk  = (__hip_bfloat16*)(ws + 16777216);   // [4096][2048] Q|K
  __hip_bfloat16* wpt = (__hip_bfloat16*)(ws + 33554432);
  __hip_bfloat16* vtg = (__hip_bfloat16*)(ws + 35651584);   // [2][16][64][2048]
  float* oacc = (float*)ws;                                 // [4096][1024] fp32 over xb+wat (dead)
  float* dacc = (float*)out;                                // [4096][16] fp32 scratch in d_out
  __hip_bfloat16* yb = vtg;                                 // final y overwrites vtg after attn
  const float SC = 0.18033688011112042f;  // (1/8) * log2(e)

  // prep: cast x (4096) + transpose w_attn (768) + transpose w_proj (256)
  prep_kernel<<<5120, 256, 0, stream>>>(x, w_attn, w_proj, xb, wat, wpt);
  // qkv GEMM: writes Q(prescaled),K into qk and V transposed into vtg
  gemm_qkv_kernel<<<dim3(24, 32), 256, 0, stream>>>(xb, wat, qk, vtg, SC);
  // zero accumulators (xb/wat dead from here; d_out scratch until proj)
  hipMemsetAsync(ws, 0, 16777216, stream);
  hipMemsetAsync(out, 0, 262144, stream);
  // attention: 2 k-parity blocks per (pair,h,b), partials via fp32 atomics
  attn_kernel<<<dim3(32, 16, 2), 256, 0, stream>>>(qk, vtg, oacc, dacc);
  // merge partials -> bf16 y (into vtg region, dead after attn)
  merge_kernel<<<4096, 256, 0, stream>>>(oacc, dacc, yb);
  // out = y @ w_proj
  gemm_bt64_kernel<float><<<dim3(16, 32), 256, 0, stream>>>(yb, wpt, out, 4096, 1024, 1024);
}

// Round 3
// 201.286 us; speedup vs baseline: 1.4306x; 1.4306x over previous
//
#include <hip/hip_runtime.h>
#include <hip/hip_bf16.h>

// B=2, T=2048, C=1024, H=16, Dh=64
// ws layout (bytes):
//   xb   [4096x1024] bf16 @ 0          (8 MB)  -- dead after qkv GEMM
//   wat  [3072x1024] bf16 @ 8388608    (6 MB)  -- dead after qkv GEMM
//   ([0,16777216) reused as oacc0 fp32 [4096][1024] during attn: parity-0 partials)
//   qk   [4096x2048] bf16 @ 16777216   (16 MB; Q cols pre-scaled by (1/8)log2e)
//   wpt  [1024x1024] bf16 @ 33554432   (2 MB)
//   vt   [2][16][64][2048] bf16 @ 35651584 (8 MB) -- reused as y bf16 after attn
// oacc1 fp32 [4096][1024] lives in d_out (scratch until proj writes it).
//   Rows t0<64 of each batch in oacc1 are mathematically zero for parity-1
//   (q-tile 0 has only k-tile 0 = parity-0) -> that 2x256KB space stores the
//   denominator partials: den(b,par,t0,h) at oacc1[b*2048*1024 + (par*2048+t0)*16 + h].

typedef __attribute__((ext_vector_type(8))) __bf16 bf16x8;
typedef __attribute__((ext_vector_type(4))) float  floatx4;
typedef __attribute__((ext_vector_type(4))) float  fvec4;
typedef __attribute__((ext_vector_type(4))) short  short4v;

#define MFMA16(a, b, c) __builtin_amdgcn_mfma_f32_16x16x32_bf16(a, b, c, 0, 0, 0)

using as1v = const __attribute__((address_space(1))) void;
using as3v = __attribute__((address_space(3))) void;
__device__ __forceinline__ void async16(const void* g, void* l) {
  __builtin_amdgcn_global_load_lds((as1v*)g, (as3v*)l, 16, 0, 0);
}

__device__ inline void store_out(float* p, float v) { *p = v; }
__device__ inline void store_out(__hip_bfloat16* p, float v) { *p = __float2bfloat16(v); }

// ---------------- fused prep: cast x; 64x64 vectorized transpose+cast of weights ----------------
__global__ __launch_bounds__(256) void prep_kernel(const float* __restrict__ x,
                                                   const float* __restrict__ w_attn,
                                                   const float* __restrict__ w_proj,
                                                   __hip_bfloat16* __restrict__ xb,
                                                   __hip_bfloat16* __restrict__ wat,
                                                   __hip_bfloat16* __restrict__ wpt) {
  const int bid = blockIdx.x, tid = threadIdx.x;
  if (bid < 4096) {  // cast x -> bf16 (4 elems/thread)
    const int i = (bid * 256 + tid) * 4;
    fvec4 v = *(const fvec4*)(x + i);
    union { short4v s; __hip_bfloat16 h[4]; } u;
#pragma unroll
    for (int j = 0; j < 4; ++j) u.h[j] = __float2bfloat16(v[j]);
    *(short4v*)((short*)xb + i) = u.s;
    return;
  }
  __shared__ __align__(16) __hip_bfloat16 tile[64 * 64];
  const float* in;
  __hip_bfloat16* out;
  int cols, bx, by;
  if (bid < 4864) {
    const int b2 = bid - 4096;
    in = w_attn; out = wat; cols = 3072; bx = b2 % 48; by = b2 / 48;
  } else {
    const int b2 = bid - 4864;
    in = w_proj; out = wpt; cols = 1024; bx = b2 % 16; by = b2 / 16;
  }
  const int c0 = bx * 64, r0 = by * 64;  // input rows = 1024
#pragma unroll
  for (int it = 0; it < 2; ++it) {
    const int c = it * 256 + tid;
    const int row = c >> 3, cg = c & 7;
    const float* src = in + (long)(r0 + row) * cols + c0 + cg * 8;
    fvec4 v0 = *(const fvec4*)src;
    fvec4 v1 = *(const fvec4*)(src + 4);
    union { bf16x8 v; __hip_bfloat16 h[8]; } u;
#pragma unroll
    for (int j = 0; j < 4; ++j) { u.h[j] = __float2bfloat16(v0[j]); u.h[4 + j] = __float2bfloat16(v1[j]); }
    *(bf16x8*)(tile + row * 64 + (cg ^ ((row >> 3) & 7)) * 8) = u.v;
  }
  __syncthreads();
#pragma unroll
  for (int it = 0; it < 2; ++it) {
    const int c = it * 256 + tid;
    const int dr = c >> 3, tg = c & 7;
    union { bf16x8 v; __hip_bfloat16 e[8]; } u;
    const int pg = (dr >> 3) ^ tg;
#pragma unroll
    for (int j = 0; j < 8; ++j)
      u.e[j] = tile[(tg * 8 + j) * 64 + pg * 8 + (dr & 7)];
    *(bf16x8*)(out + (long)(c0 + dr) * 1024 + r0 + tg * 8) = u.v;
  }
}

// ------------- qkv GEMM: A[4096,1024] x wat^T -> qk[4096,2048] + vt (V transposed) -------------
__global__ __launch_bounds__(256) void gemm_qkv_kernel(const __hip_bfloat16* __restrict__ A,
                                                       const __hip_bfloat16* __restrict__ Bt,
                                                       __hip_bfloat16* __restrict__ qk,
                                                       __hip_bfloat16* __restrict__ vt,
                                                       float qscale) {
  const int K = 1024;
  __shared__ __align__(16) __hip_bfloat16 As[2][128 * 32];
  __shared__ __align__(16) __hip_bfloat16 Bs[2][128 * 32];
  const int tid = threadIdx.x;
  const int lane = tid & 63, wv = tid >> 6;
  const int l15 = lane & 15, quad = lane >> 4;
  const int wm = wv >> 1, wn = wv & 1;
  const long m0 = (long)blockIdx.y * 128, n0 = (long)blockIdx.x * 128;
  floatx4 acc[4][4] = {};
  const int nk = K >> 5;

  auto issue = [&](int kt, int p) {
    const int k0 = kt << 5;
#pragma unroll
    for (int it = 0; it < 2; ++it) {
      const int c = it * 256 + tid;
      const int row = c >> 2;
      const int lcg = (c & 3) ^ ((row >> 1) & 3);
      async16(A + (m0 + row) * K + k0 + lcg * 8, (char*)&As[p][0] + c * 16);
      async16(Bt + (n0 + row) * K + k0 + lcg * 8, (char*)&Bs[p][0] + c * 16);
    }
  };

  issue(0, 0);
  for (int kt = 0; kt < nk; ++kt) {
    const int p = kt & 1;
    __syncthreads();
    if (kt + 1 < nk) issue(kt + 1, p ^ 1);
    bf16x8 af[4], bfr[4];
#pragma unroll
    for (int t = 0; t < 4; ++t) {
      const int ar = wm * 64 + t * 16 + l15;
      const int br = wn * 64 + t * 16 + l15;
      af[t]  = *(const bf16x8*)(&As[p][ar * 32 + (quad ^ ((ar >> 1) & 3)) * 8]);
      bfr[t] = *(const bf16x8*)(&Bs[p][br * 32 + (quad ^ ((br >> 1) & 3)) * 8]);
    }
#pragma unroll
    for (int mt = 0; mt < 4; ++mt)
#pragma unroll
      for (int nt = 0; nt < 4; ++nt)
        acc[mt][nt] = MFMA16(af[mt], bfr[nt], acc[mt][nt]);
  }

#pragma unroll
  for (int nt = 0; nt < 4; ++nt) {
    const int colb = (int)n0 + wn * 64 + nt * 16;  // wave-uniform, multiple of 16
    if (colb >= 2048) {
      const int hh = (colb - 2048) >> 6;
      const int d  = (colb & 63) + l15;
#pragma unroll
      for (int mt = 0; mt < 4; ++mt) {
        const long row = m0 + wm * 64 + mt * 16 + quad * 4;
        const long b   = row >> 11;
        const long t0  = row & 2047;
        union { short4v s; __hip_bfloat16 h[4]; } uy;
#pragma unroll
        for (int r = 0; r < 4; ++r) uy.h[r] = __float2bfloat16(acc[mt][nt][r]);
        *(short4v*)(vt + ((b * 16 + hh) * 64 + d) * 2048 + t0) = uy.s;
      }
    } else {
      const float sc = (colb < 1024) ? qscale : 1.0f;
      const long col = colb + l15;
#pragma unroll
      for (int mt = 0; mt < 4; ++mt)
#pragma unroll
        for (int r = 0; r < 4; ++r) {
          const long row = m0 + wm * 64 + mt * 16 + quad * 4 + r;
          qk[row * 2048 + col] = __float2bfloat16(acc[mt][nt][r] * sc);
        }
    }
  }
}

// ------------- GEMM 128x64 (proj) -------------
template <typename OutT>
__global__ __launch_bounds__(256) void gemm_bt64_kernel(const __hip_bfloat16* __restrict__ A,
                                                        const __hip_bfloat16* __restrict__ Bt,
                                                        OutT* __restrict__ C,
                                                        int M, int N, int K) {
  __shared__ __align__(16) __hip_bfloat16 As[2][128 * 32];
  __shared__ __align__(16) __hip_bfloat16 Bs[2][64 * 32];
  const int tid = threadIdx.x;
  const int lane = tid & 63, wv = tid >> 6;
  const int l15 = lane & 15, quad = lane >> 4;
  const int wm = wv >> 1, wn = wv & 1;
  const long m0 = (long)blockIdx.y * 128, n0 = (long)blockIdx.x * 64;
  floatx4 acc[4][2] = {};
  const int nk = K >> 5;

  auto issue = [&](int kt, int p) {
    const int k0 = kt << 5;
#pragma unroll
    for (int it = 0; it < 2; ++it) {
      const int c = it * 256 + tid;
      const int row = c >> 2;
      const int lcg = (c & 3) ^ ((row >> 1) & 3);
      async16(A + (m0 + row) * K + k0 + lcg * 8, (char*)&As[p][0] + c * 16);
    }
    {
      const int c = tid;
      const int row = c >> 2;
      const int lcg = (c & 3) ^ ((row >> 1) & 3);
      async16(Bt + (n0 + row) * K + k0 + lcg * 8, (char*)&Bs[p][0] + c * 16);
    }
  };

  issue(0, 0);
  for (int kt = 0; kt < nk; ++kt) {
    const int p = kt & 1;
    __syncthreads();
    if (kt + 1 < nk) issue(kt + 1, p ^ 1);
    bf16x8 af[4], bfr[2];
#pragma unroll
    for (int t = 0; t < 4; ++t) {
      const int ar = wm * 64 + t * 16 + l15;
      af[t] = *(const bf16x8*)(&As[p][ar * 32 + (quad ^ ((ar >> 1) & 3)) * 8]);
    }
#pragma unroll
    for (int t = 0; t < 2; ++t) {
      const int br = wn * 32 + t * 16 + l15;
      bfr[t] = *(const bf16x8*)(&Bs[p][br * 32 + (quad ^ ((br >> 1) & 3)) * 8]);
    }
#pragma unroll
    for (int mt = 0; mt < 4; ++mt)
#pragma unroll
      for (int nt = 0; nt < 2; ++nt)
        acc[mt][nt] = MFMA16(af[mt], bfr[nt], acc[mt][nt]);
  }
#pragma unroll
  for (int mt = 0; mt < 4; ++mt)
#pragma unroll
    for (int nt = 0; nt < 2; ++nt)
#pragma unroll
      for (int r = 0; r < 4; ++r) {
        const long row = m0 + wm * 64 + mt * 16 + quad * 4 + r;
        const long col = n0 + wn * 32 + nt * 16 + l15;
        store_out(C + row * N + col, acc[mt][nt][r]);
      }
}

// ------------- paired-tile flash attention, k-parity split at BLOCK level, store-based merge -----
// Verified round-2 body; epilogue now PLAIN STORES (no atomics, no memset):
//   parity-0 o-partials -> oacc0 (ws), parity-1 -> oacc1 (d_out),
//   denominator partials -> oacc1's guaranteed-zero rows (t0<64 of each batch).
// Grid 1024 blocks, LDS 40KB -> target 4 blocks/CU = 16 waves/CU.
__global__ __launch_bounds__(256) void attn_kernel(const __hip_bfloat16* __restrict__ qk,
                                                   const __hip_bfloat16* __restrict__ vtg,
                                                   float* __restrict__ oacc0,
                                                   float* __restrict__ oacc1) {
  __shared__ __align__(16) __hip_bfloat16 Ks[2][64 * 64];
  __shared__ __align__(16) __hip_bfloat16 Vt[2][64 * 64];
  __shared__ __align__(16) __hip_bfloat16 Pb[4][16 * 64];  // per-wave P[q][k]
  const int tid = threadIdx.x;
  const int lane = tid & 63, wv = tid >> 6;
  const int l15 = lane & 15, quad = lane >> 4;
  const int pt = blockIdx.x >> 1, par = blockIdx.x & 1;
  const int h = blockIdx.y, b = blockIdx.z;
  const int qtA = pt, qtB = 31 - pt;
  const int q0A = qtA * 64, q0B = qtB * 64;
  const long bh = (long)b * 16 + h;
  const long RS = 2048;

  auto issue = [&](int kt, int p) {
    const int kb = kt * 64;
#pragma unroll
    for (int it = 0; it < 2; ++it) {
      const int c = it * 256 + tid;
      const int row = c >> 3;
      const int cg = (c & 7) ^ (row & 7);
      async16(qk + ((long)b * 2048 + kb + row) * RS + 1024 + h * 64 + cg * 8,
              (char*)&Ks[p][0] + c * 16);
      async16(vtg + (bh * 64 + row) * 2048 + kb + cg * 8, (char*)&Vt[p][0] + c * 16);
    }
  };

  bf16x8 bqA0, bqA1, bqB0, bqB1;
  {
    const __hip_bfloat16* qpA = qk + ((long)b * 2048 + q0A + wv * 16 + l15) * RS + h * 64 + quad * 8;
    bqA0 = *(const bf16x8*)qpA;
    bqA1 = *(const bf16x8*)(qpA + 32);
    const __hip_bfloat16* qpB = qk + ((long)b * 2048 + q0B + wv * 16 + l15) * RS + h * 64 + quad * 8;
    bqB0 = *(const bf16x8*)qpB;
    bqB1 = *(const bf16x8*)(qpB + 32);
  }
  union { bf16x8 v; __hip_bfloat16 e[8]; } uo;
#pragma unroll
  for (int j = 0; j < 8; ++j) uo.e[j] = __float2bfloat16(1.0f);
  const bf16x8 ones = uo.v;

  floatx4 oA[4] = {}, oB[4] = {}, o4A = {}, o4B = {};
  __hip_bfloat16* Pw = &Pb[wv][0];
  const int m7 = l15 & 7;

  issue(par, 0);
  int bufp = 0;
  for (int kt = par; kt <= qtB; kt += 2, bufp ^= 1) {
    const int kb = kt * 64;
    const bool actA = (kt <= qtA);
    __syncthreads();
    if (kt + 2 <= qtB) issue(kt + 2, bufp ^ 1);

    bf16x8 kf[4][2], vf[4][2];
#pragma unroll
    for (int nt = 0; nt < 4; ++nt) {
      const int row = nt * 16 + l15;
      const int s0 = (quad ^ (row & 7)) * 8, s1 = ((quad + 4) ^ (row & 7)) * 8;
      kf[nt][0] = *(const bf16x8*)(&Ks[bufp][row * 64 + s0]);
      kf[nt][1] = *(const bf16x8*)(&Ks[bufp][row * 64 + s1]);
      vf[nt][0] = *(const bf16x8*)(&Vt[bufp][row * 64 + s0]);
      vf[nt][1] = *(const bf16x8*)(&Vt[bufp][row * 64 + s1]);
    }

    auto tile = [&](const bf16x8& bq0, const bf16x8& bq1, floatx4* o, floatx4& o4,
                    bool diag, int q0X) {
      floatx4 st[4] = {};
#pragma unroll
      for (int nt = 0; nt < 4; ++nt) {
        st[nt] = MFMA16(kf[nt][0], bq0, st[nt]);
        st[nt] = MFMA16(kf[nt][1], bq1, st[nt]);
      }
      const int qg = q0X + wv * 16 + l15;
#pragma unroll
      for (int nt = 0; nt < 4; ++nt) {
        union { short4v s; __hip_bfloat16 h[4]; } up;
#pragma unroll
        for (int r = 0; r < 4; ++r) {
          float pv = exp2f(st[nt][r]);
          if (diag && (kb + nt * 16 + quad * 4 + r > qg)) pv = 0.f;
          up.h[r] = __float2bfloat16(pv);
        }
        const int chunk = (nt * 2 + (quad >> 1)) ^ m7;
        *(short4v*)(Pw + l15 * 64 + chunk * 8 + (quad & 1) * 4) = up.s;
      }
      const bf16x8 pb0 = *(const bf16x8*)(Pw + l15 * 64 + (quad ^ m7) * 8);
      const bf16x8 pb1 = *(const bf16x8*)(Pw + l15 * 64 + ((quad + 4) ^ m7) * 8);
#pragma unroll
      for (int mt = 0; mt < 4; ++mt) {
        o[mt] = MFMA16(vf[mt][0], pb0, o[mt]);
        o[mt] = MFMA16(vf[mt][1], pb1, o[mt]);
      }
      o4 = MFMA16(ones, pb0, o4);
      o4 = MFMA16(ones, pb1, o4);
    };

    tile(bqB0, bqB1, oB, o4B, kt == qtB, q0B);
    if (actA) tile(bqA0, bqA1, oA, o4A, kt == qtA, q0A);
  }

  // plain-store epilogue: o-partials to this parity's buffer; denom partials to
  // oacc1's zero rows (t0<64). No atomics; all addresses disjoint across blocks.
  auto epi = [&](floatx4* o, floatx4& o4, int q0X) {
    const int t0 = q0X + wv * 16 + l15;
    const long t = (long)b * 2048 + t0;
    float* dst = (par ? oacc1 : oacc0) + t * 1024 + h * 64 + quad * 4;
#pragma unroll
    for (int mt = 0; mt < 4; ++mt)
      *(floatx4*)(dst + mt * 16) = o[mt];
    if (quad == 0)
      oacc1[(long)b * (2048 * 1024) + ((par * 2048 + t0) * 16 + h)] = o4[0];
  };
  epi(oB, o4B, q0B);
  if (!(par == 1 && qtA == 0)) epi(oA, o4A, q0A);  // parity-1, q-tile 0: no k-tiles
}

// ------------- merge: y = (o0 + o1) / (d0 + d1), cast bf16 -------------
__global__ __launch_bounds__(256) void merge_kernel(const float* __restrict__ oacc0,
                                                    const float* __restrict__ oacc1,
                                                    __hip_bfloat16* __restrict__ y) {
  const int i = (blockIdx.x * 256 + threadIdx.x) * 4;
  const int row = i >> 10;           // global t index 0..4095
  const int t0 = row & 2047, bb = row >> 11, hh = (i >> 6) & 15;
  const long dbase = (long)bb * (2048 * 1024);
  float den = oacc1[dbase + (t0 * 16 + hh)];       // parity-0 denom
  fvec4 v = *(const fvec4*)(oacc0 + i);
  if (t0 >= 64) {                                   // parity-1 contributed
    den += oacc1[dbase + ((2048 + t0) * 16 + hh)];
    v += *(const fvec4*)(oacc1 + i);
  }
  const float inv = 1.0f / den;
  union { short4v s; __hip_bfloat16 h[4]; } u;
#pragma unroll
  for (int j = 0; j < 4; ++j) u.h[j] = __float2bfloat16(v[j] * inv);
  *(short4v*)((short*)y + i) = u.s;
}

extern "C" void kernel_launch(void* const* d_in, const int* in_sizes, int n_in,
                              void* d_out, int out_size, void* d_ws, size_t ws_size,
                              hipStream_t stream) {
  const float* x      = (const float*)d_in[0];
  const float* w_attn = (const float*)d_in[1];
  const float* w_proj = (const float*)d_in[2];
  float* out = (float*)d_out;
  char* ws = (char*)d_ws;
  __hip_bfloat16* xb  = (__hip_bfloat16*)(ws);
  __hip_bfloat16* wat = (__hip_bfloat16*)(ws + 8388608);
  __hip_bfloat16* qk  = (__hip_bfloat16*)(ws + 16777216);   // [4096][2048] Q|K
  __hip_bfloat16* wpt = (__hip_bfloat16*)(ws + 33554432);
  __hip_bfloat16* vtg = (__hip_bfloat16*)(ws + 35651584);   // [2][16][64][2048]
  float* oacc0 = (float*)ws;        // [4096][1024] fp32 over xb+wat (dead during attn)
  float* oacc1 = (float*)out;       // [4096][1024] fp32 in d_out (scratch until proj)
  __hip_bfloat16* yb = vtg;         // final y overwrites vtg after attn
  const float SC = 0.18033688011112042f;  // (1/8) * log2(e)

  // prep: cast x (4096) + transpose w_attn (768) + transpose w_proj (256)
  prep_kernel<<<5120, 256, 0, stream>>>(x, w_attn, w_proj, xb, wat, wpt);
  // qkv GEMM: writes Q(prescaled),K into qk and V transposed into vtg
  gemm_qkv_kernel<<<dim3(24, 32), 256, 0, stream>>>(xb, wat, qk, vtg, SC);
  // attention: 2 k-parity blocks per (pair,h,b); partials via plain stores
  attn_kernel<<<dim3(32, 16, 2), 256, 0, stream>>>(qk, vtg, oacc0, oacc1);
  // merge partials -> bf16 y (into vtg region, dead after attn)
  merge_kernel<<<4096, 256, 0, stream>>>(oacc0, oacc1, yb);
  // out = y @ w_proj (overwrites oacc1 region after merge consumed it)
  gemm_bt64_kernel<float><<<dim3(16, 32), 256, 0, stream>>>(yb, wpt, out, 4096, 1024, 1024);
}

// Round 4
// 181.345 us; speedup vs baseline: 1.5879x; 1.1100x over previous
//
#include <hip/hip_runtime.h>
#include <hip/hip_bf16.h>

// B=2, T=2048, C=1024, H=16, Dh=64
// ws layout (bytes), total 43,646,976 (qkv holds Q,K only; V goes straight to vt):
//   xb   [4096x1024] bf16 @ 0          (8 MB)
//   wat  [3072x1024] bf16 @ 8388608    (6 MB) -- reused as yb [4096x1024] after qkv GEMM
//   qk   [4096x2048] bf16 @ 16777216   (16 MB; Q cols pre-scaled by (1/8)log2e)
//   wpt  [1024x1024] bf16 @ 33554432   (2 MB)
//   vt   [2][16][64][2048] bf16 @ 35651584 (8 MB)

typedef __attribute__((ext_vector_type(8))) __bf16 bf16x8;
typedef __attribute__((ext_vector_type(4))) float  floatx4;
typedef __attribute__((ext_vector_type(4))) float  fvec4;
typedef __attribute__((ext_vector_type(4))) short  short4v;

#define MFMA16(a, b, c) __builtin_amdgcn_mfma_f32_16x16x32_bf16(a, b, c, 0, 0, 0)

using as1v = const __attribute__((address_space(1))) void;
using as3v = __attribute__((address_space(3))) void;
__device__ __forceinline__ void async16(const void* g, void* l) {
  __builtin_amdgcn_global_load_lds((as1v*)g, (as3v*)l, 16, 0, 0);
}

__device__ inline void store_out(float* p, float v) { *p = v; }
__device__ inline void store_out(__hip_bfloat16* p, float v) { *p = __float2bfloat16(v); }

// ---------------- fused prep: cast x; 64x64 vectorized transpose+cast of weights ----------------
__global__ __launch_bounds__(256) void prep_kernel(const float* __restrict__ x,
                                                   const float* __restrict__ w_attn,
                                                   const float* __restrict__ w_proj,
                                                   __hip_bfloat16* __restrict__ xb,
                                                   __hip_bfloat16* __restrict__ wat,
                                                   __hip_bfloat16* __restrict__ wpt) {
  const int bid = blockIdx.x, tid = threadIdx.x;
  if (bid < 4096) {  // cast x -> bf16 (4 elems/thread)
    const int i = (bid * 256 + tid) * 4;
    fvec4 v = *(const fvec4*)(x + i);
    union { short4v s; __hip_bfloat16 h[4]; } u;
#pragma unroll
    for (int j = 0; j < 4; ++j) u.h[j] = __float2bfloat16(v[j]);
    *(short4v*)((short*)xb + i) = u.s;
    return;
  }
  __shared__ __align__(16) __hip_bfloat16 tile[64 * 64];
  const float* in;
  __hip_bfloat16* out;
  int cols, bx, by;
  if (bid < 4864) {
    const int b2 = bid - 4096;
    in = w_attn; out = wat; cols = 3072; bx = b2 % 48; by = b2 / 48;
  } else {
    const int b2 = bid - 4864;
    in = w_proj; out = wpt; cols = 1024; bx = b2 % 16; by = b2 / 16;
  }
  const int c0 = bx * 64, r0 = by * 64;  // input rows = 1024
#pragma unroll
  for (int it = 0; it < 2; ++it) {
    const int c = it * 256 + tid;
    const int row = c >> 3, cg = c & 7;
    const float* src = in + (long)(r0 + row) * cols + c0 + cg * 8;
    fvec4 v0 = *(const fvec4*)src;
    fvec4 v1 = *(const fvec4*)(src + 4);
    union { bf16x8 v; __hip_bfloat16 h[8]; } u;
#pragma unroll
    for (int j = 0; j < 4; ++j) { u.h[j] = __float2bfloat16(v0[j]); u.h[4 + j] = __float2bfloat16(v1[j]); }
    *(bf16x8*)(tile + row * 64 + (cg ^ ((row >> 3) & 7)) * 8) = u.v;
  }
  __syncthreads();
#pragma unroll
  for (int it = 0; it < 2; ++it) {
    const int c = it * 256 + tid;
    const int dr = c >> 3, tg = c & 7;
    union { bf16x8 v; __hip_bfloat16 e[8]; } u;
    const int pg = (dr >> 3) ^ tg;
#pragma unroll
    for (int j = 0; j < 8; ++j)
      u.e[j] = tile[(tg * 8 + j) * 64 + pg * 8 + (dr & 7)];
    *(bf16x8*)(out + (long)(c0 + dr) * 1024 + r0 + tg * 8) = u.v;
  }
}

// ------------- qkv GEMM: A[4096,1024] x wat^T -> qk[4096,2048] + vt (V transposed) -------------
__global__ __launch_bounds__(256) void gemm_qkv_kernel(const __hip_bfloat16* __restrict__ A,
                                                       const __hip_bfloat16* __restrict__ Bt,
                                                       __hip_bfloat16* __restrict__ qk,
                                                       __hip_bfloat16* __restrict__ vt,
                                                       float qscale) {
  const int K = 1024;
  __shared__ __align__(16) __hip_bfloat16 As[2][128 * 32];
  __shared__ __align__(16) __hip_bfloat16 Bs[2][128 * 32];
  const int tid = threadIdx.x;
  const int lane = tid & 63, wv = tid >> 6;
  const int l15 = lane & 15, quad = lane >> 4;
  const int wm = wv >> 1, wn = wv & 1;
  const long m0 = (long)blockIdx.y * 128, n0 = (long)blockIdx.x * 128;
  floatx4 acc[4][4] = {};
  const int nk = K >> 5;

  auto issue = [&](int kt, int p) {
    const int k0 = kt << 5;
#pragma unroll
    for (int it = 0; it < 2; ++it) {
      const int c = it * 256 + tid;
      const int row = c >> 2;
      const int lcg = (c & 3) ^ ((row >> 1) & 3);
      async16(A + (m0 + row) * K + k0 + lcg * 8, (char*)&As[p][0] + c * 16);
      async16(Bt + (n0 + row) * K + k0 + lcg * 8, (char*)&Bs[p][0] + c * 16);
    }
  };

  issue(0, 0);
  for (int kt = 0; kt < nk; ++kt) {
    const int p = kt & 1;
    __syncthreads();
    if (kt + 1 < nk) issue(kt + 1, p ^ 1);
    bf16x8 af[4], bfr[4];
#pragma unroll
    for (int t = 0; t < 4; ++t) {
      const int ar = wm * 64 + t * 16 + l15;
      const int br = wn * 64 + t * 16 + l15;
      af[t]  = *(const bf16x8*)(&As[p][ar * 32 + (quad ^ ((ar >> 1) & 3)) * 8]);
      bfr[t] = *(const bf16x8*)(&Bs[p][br * 32 + (quad ^ ((br >> 1) & 3)) * 8]);
    }
#pragma unroll
    for (int mt = 0; mt < 4; ++mt)
#pragma unroll
      for (int nt = 0; nt < 4; ++nt)
        acc[mt][nt] = MFMA16(af[mt], bfr[nt], acc[mt][nt]);
  }

#pragma unroll
  for (int nt = 0; nt < 4; ++nt) {
    const int colb = (int)n0 + wn * 64 + nt * 16;  // wave-uniform, multiple of 16
    if (colb >= 2048) {
      const int hh = (colb - 2048) >> 6;
      const int d  = (colb & 63) + l15;
#pragma unroll
      for (int mt = 0; mt < 4; ++mt) {
        const long row = m0 + wm * 64 + mt * 16 + quad * 4;
        const long b   = row >> 11;
        const long t0  = row & 2047;
        union { short4v s; __hip_bfloat16 h[4]; } uy;
#pragma unroll
        for (int r = 0; r < 4; ++r) uy.h[r] = __float2bfloat16(acc[mt][nt][r]);
        *(short4v*)(vt + ((b * 16 + hh) * 64 + d) * 2048 + t0) = uy.s;
      }
    } else {
      const float sc = (colb < 1024) ? qscale : 1.0f;
      const long col = colb + l15;
#pragma unroll
      for (int mt = 0; mt < 4; ++mt)
#pragma unroll
        for (int r = 0; r < 4; ++r) {
          const long row = m0 + wm * 64 + mt * 16 + quad * 4 + r;
          qk[row * 2048 + col] = __float2bfloat16(acc[mt][nt][r] * sc);
        }
    }
  }
}

// ------------- GEMM 128x64 (proj) -------------
template <typename OutT>
__global__ __launch_bounds__(256) void gemm_bt64_kernel(const __hip_bfloat16* __restrict__ A,
                                                        const __hip_bfloat16* __restrict__ Bt,
                                                        OutT* __restrict__ C,
                                                        int M, int N, int K) {
  __shared__ __align__(16) __hip_bfloat16 As[2][128 * 32];
  __shared__ __align__(16) __hip_bfloat16 Bs[2][64 * 32];
  const int tid = threadIdx.x;
  const int lane = tid & 63, wv = tid >> 6;
  const int l15 = lane & 15, quad = lane >> 4;
  const int wm = wv >> 1, wn = wv & 1;
  const long m0 = (long)blockIdx.y * 128, n0 = (long)blockIdx.x * 64;
  floatx4 acc[4][2] = {};
  const int nk = K >> 5;

  auto issue = [&](int kt, int p) {
    const int k0 = kt << 5;
#pragma unroll
    for (int it = 0; it < 2; ++it) {
      const int c = it * 256 + tid;
      const int row = c >> 2;
      const int lcg = (c & 3) ^ ((row >> 1) & 3);
      async16(A + (m0 + row) * K + k0 + lcg * 8, (char*)&As[p][0] + c * 16);
    }
    {
      const int c = tid;
      const int row = c >> 2;
      const int lcg = (c & 3) ^ ((row >> 1) & 3);
      async16(Bt + (n0 + row) * K + k0 + lcg * 8, (char*)&Bs[p][0] + c * 16);
    }
  };

  issue(0, 0);
  for (int kt = 0; kt < nk; ++kt) {
    const int p = kt & 1;
    __syncthreads();
    if (kt + 1 < nk) issue(kt + 1, p ^ 1);
    bf16x8 af[4], bfr[2];
#pragma unroll
    for (int t = 0; t < 4; ++t) {
      const int ar = wm * 64 + t * 16 + l15;
      af[t] = *(const bf16x8*)(&As[p][ar * 32 + (quad ^ ((ar >> 1) & 3)) * 8]);
    }
#pragma unroll
    for (int t = 0; t < 2; ++t) {
      const int br = wn * 32 + t * 16 + l15;
      bfr[t] = *(const bf16x8*)(&Bs[p][br * 32 + (quad ^ ((br >> 1) & 3)) * 8]);
    }
#pragma unroll
    for (int mt = 0; mt < 4; ++mt)
#pragma unroll
      for (int nt = 0; nt < 2; ++nt)
        acc[mt][nt] = MFMA16(af[mt], bfr[nt], acc[mt][nt]);
  }
#pragma unroll
  for (int mt = 0; mt < 4; ++mt)
#pragma unroll
    for (int nt = 0; nt < 2; ++nt)
#pragma unroll
      for (int r = 0; r < 4; ++r) {
        const long row = m0 + wm * 64 + mt * 16 + quad * 4 + r;
        const long col = n0 + wn * 32 + nt * 16 + l15;
        store_out(C + row * N + col, acc[mt][nt][r]);
      }
}

// ------------- paired-tile flash attention, 8 waves, k-parity split across wave groups -------------
// Round-1 verified body. LDS (80 KB): K[2 pairbuf][2 parity][64*64] 32KB | V same 32KB |
// Pb[8][16*64] 16KB. 2 blocks/CU (80KBx2 = 160KiB exact-fit, residency PROVEN round 1:
// occupancy 40%) -> 16 waves/CU. __launch_bounds__(512, 2): hipcc's 2nd arg is CUDA-style
// min-BLOCKS/CU (measured round 1: (512,4) -> 64 VGPR = 8 waves/SIMD cap), so 2 blocks
// -> 4 waves/SIMD -> 128-VGPR cap; body naturally uses ~108 (round 0) -> no spill.
__global__ __launch_bounds__(512, 2) void attn_kernel(const __hip_bfloat16* __restrict__ qk,
                                                      const __hip_bfloat16* __restrict__ vtg,
                                                      __hip_bfloat16* __restrict__ y) {
  __shared__ __align__(16) char smem[81920];
  __hip_bfloat16* KsB = (__hip_bfloat16*)smem;            // [2][2][4096]
  __hip_bfloat16* VtB = (__hip_bfloat16*)(smem + 32768);  // [2][2][4096]
  __hip_bfloat16* PbB = (__hip_bfloat16*)(smem + 65536);  // [8][16*64]

  const int tid = threadIdx.x;
  const int lane = tid & 63, wv = tid >> 6;
  const int l15 = lane & 15, quad = lane >> 4;
  const int g = wv >> 2, sub = wv & 3;  // g: k-parity group, sub: q sub-tile
  const int pt = blockIdx.x, h = blockIdx.y, b = blockIdx.z;
  const int qtA = pt, qtB = 31 - pt;
  const int q0A = qtA * 64, q0B = qtB * 64;
  const long bh = (long)b * 16 + h;
  const long RS = 2048;

  // staging: thread -> (row, colgroup) fixed; bases hoisted out of the loop
  const int srow = tid >> 3;
  const int scg = (tid & 7) ^ (srow & 7);
  const __hip_bfloat16* kbase = qk + ((long)b * 2048 + srow) * RS + 1024 + h * 64 + scg * 8;
  const __hip_bfloat16* vbase = vtg + (bh * 64 + srow) * 2048 + scg * 8;
  char* ldst = smem + tid * 16;  // K dest; V dest at +32768

  auto issue = [&](int pr, int buf) {
#pragma unroll
    for (int par = 0; par < 2; ++par) {
      const int kt = 2 * pr + par;
      if (kt <= qtB) {
        const long kb = (long)kt * 64;
        async16(kbase + kb * RS, ldst + buf * 16384 + par * 8192);
        async16(vbase + kb,      ldst + 32768 + buf * 16384 + par * 8192);
      }
    }
  };

  bf16x8 bqA0, bqA1, bqB0, bqB1;
  {
    const __hip_bfloat16* qpA = qk + ((long)b * 2048 + q0A + sub * 16 + l15) * RS + h * 64 + quad * 8;
    bqA0 = *(const bf16x8*)qpA;
    bqA1 = *(const bf16x8*)(qpA + 32);
    const __hip_bfloat16* qpB = qk + ((long)b * 2048 + q0B + sub * 16 + l15) * RS + h * 64 + quad * 8;
    bqB0 = *(const bf16x8*)qpB;
    bqB1 = *(const bf16x8*)(qpB + 32);
  }
  union { bf16x8 v; __hip_bfloat16 e[8]; } uo;
#pragma unroll
  for (int j = 0; j < 8; ++j) uo.e[j] = __float2bfloat16(1.0f);
  const bf16x8 ones = uo.v;

  floatx4 oA[4] = {}, oB[4] = {}, o4A = {}, o4B = {};
  __hip_bfloat16* Pw = PbB + wv * (16 * 64);
  const int m7 = l15 & 7;

  const int npairs = (qtB + 2) >> 1;
  issue(0, 0);
  for (int pr = 0; pr < npairs; ++pr) {
    const int buf = pr & 1;
    __syncthreads();
    if (pr + 1 < npairs) issue(pr + 1, buf ^ 1);
    const int kt = 2 * pr + g;
    if (kt > qtB) continue;  // wave-uniform; barriers still hit uniformly at loop top
    const int kb = kt * 64;
    const __hip_bfloat16* Ksp = KsB + buf * 8192 + g * 4096;
    const __hip_bfloat16* Vsp = VtB + buf * 8192 + g * 4096;

    bf16x8 kf[4][2], vf[4][2];
#pragma unroll
    for (int nt = 0; nt < 4; ++nt) {
      const int row = nt * 16 + l15;
      const int s0 = (quad ^ (row & 7)) * 8, s1 = ((quad + 4) ^ (row & 7)) * 8;
      kf[nt][0] = *(const bf16x8*)(Ksp + row * 64 + s0);
      kf[nt][1] = *(const bf16x8*)(Ksp + row * 64 + s1);
      vf[nt][0] = *(const bf16x8*)(Vsp + row * 64 + s0);
      vf[nt][1] = *(const bf16x8*)(Vsp + row * 64 + s1);
    }

    auto tile = [&](const bf16x8& bq0, const bf16x8& bq1, floatx4* o, floatx4& o4,
                    bool diag, int q0X) {
      floatx4 st[4] = {};
#pragma unroll
      for (int nt = 0; nt < 4; ++nt) {
        st[nt] = MFMA16(kf[nt][0], bq0, st[nt]);
        st[nt] = MFMA16(kf[nt][1], bq1, st[nt]);
      }
      if (diag) {  // uniform branch: mask ops only on the ~2 diagonal tiles per block
        const int qg = q0X + sub * 16 + l15;
#pragma unroll
        for (int nt = 0; nt < 4; ++nt) {
          union { short4v s; __hip_bfloat16 h[4]; } up;
#pragma unroll
          for (int r = 0; r < 4; ++r) {
            float pv = exp2f(st[nt][r]);
            if (kb + nt * 16 + quad * 4 + r > qg) pv = 0.f;
            up.h[r] = __float2bfloat16(pv);
          }
          const int chunk = (nt * 2 + (quad >> 1)) ^ m7;
          *(short4v*)(Pw + l15 * 64 + chunk * 8 + (quad & 1) * 4) = up.s;
        }
      } else {
#pragma unroll
        for (int nt = 0; nt < 4; ++nt) {
          union { short4v s; __hip_bfloat16 h[4]; } up;
#pragma unroll
          for (int r = 0; r < 4; ++r) up.h[r] = __float2bfloat16(exp2f(st[nt][r]));
          const int chunk = (nt * 2 + (quad >> 1)) ^ m7;
          *(short4v*)(Pw + l15 * 64 + chunk * 8 + (quad & 1) * 4) = up.s;
        }
      }
      const bf16x8 pb0 = *(const bf16x8*)(Pw + l15 * 64 + (quad ^ m7) * 8);
      const bf16x8 pb1 = *(const bf16x8*)(Pw + l15 * 64 + ((quad + 4) ^ m7) * 8);
#pragma unroll
      for (int mt = 0; mt < 4; ++mt) {
        o[mt] = MFMA16(vf[mt][0], pb0, o[mt]);
        o[mt] = MFMA16(vf[mt][1], pb1, o[mt]);
      }
      o4 = MFMA16(ones, pb0, o4);
      o4 = MFMA16(ones, pb1, o4);
    };

    tile(bqB0, bqB1, oB, o4B, kt == qtB, q0B);
    if (kt <= qtA) tile(bqA0, bqA1, oA, o4A, kt == qtA, q0A);
  }

  // merge parity groups: group 1 -> LDS, group 0 adds and writes out
  __syncthreads();
  floatx4* redv = (floatx4*)smem;  // [4 sub][10][64 lane] floatx4 = 40 KB (over Ks/Vt, now dead)
  if (g == 1) {
#pragma unroll
    for (int mt = 0; mt < 4; ++mt) {
      redv[(sub * 10 + mt) * 64 + lane] = oA[mt];
      redv[(sub * 10 + 4 + mt) * 64 + lane] = oB[mt];
    }
    redv[(sub * 10 + 8) * 64 + lane] = o4A;
    redv[(sub * 10 + 9) * 64 + lane] = o4B;
  }
  __syncthreads();
  if (g == 0) {
#pragma unroll
    for (int mt = 0; mt < 4; ++mt) {
      oA[mt] += redv[(sub * 10 + mt) * 64 + lane];
      oB[mt] += redv[(sub * 10 + 4 + mt) * 64 + lane];
    }
    o4A += redv[(sub * 10 + 8) * 64 + lane];
    o4B += redv[(sub * 10 + 9) * 64 + lane];

    auto epi = [&](floatx4* o, floatx4& o4, int q0X) {
      const float inv = 1.0f / o4[0];
      const long t = (long)b * 2048 + q0X + sub * 16 + l15;
#pragma unroll
      for (int mt = 0; mt < 4; ++mt) {
        union { short4v s; __hip_bfloat16 h[4]; } uy;
#pragma unroll
        for (int r = 0; r < 4; ++r) uy.h[r] = __float2bfloat16(o[mt][r] * inv);
        *(short4v*)(y + t * 1024 + h * 64 + mt * 16 + quad * 4) = uy.s;
      }
    };
    epi(oA, o4A, q0A);
    epi(oB, o4B, q0B);
  }
}

extern "C" void kernel_launch(void* const* d_in, const int* in_sizes, int n_in,
                              void* d_out, int out_size, void* d_ws, size_t ws_size,
                              hipStream_t stream) {
  const float* x      = (const float*)d_in[0];
  const float* w_attn = (const float*)d_in[1];
  const float* w_proj = (const float*)d_in[2];
  float* out = (float*)d_out;
  char* ws = (char*)d_ws;
  __hip_bfloat16* xb  = (__hip_bfloat16*)(ws);
  __hip_bfloat16* wat = (__hip_bfloat16*)(ws + 8388608);    // reused as yb after qkv GEMM
  __hip_bfloat16* qk  = (__hip_bfloat16*)(ws + 16777216);   // [4096][2048] Q|K
  __hip_bfloat16* wpt = (__hip_bfloat16*)(ws + 33554432);
  __hip_bfloat16* vtg = (__hip_bfloat16*)(ws + 35651584);   // [2][16][64][2048]
  __hip_bfloat16* yb  = wat;
  const float SC = 0.18033688011112042f;  // (1/8) * log2(e)

  // prep: cast x (4096) + transpose w_attn (768) + transpose w_proj (256)
  prep_kernel<<<5120, 256, 0, stream>>>(x, w_attn, w_proj, xb, wat, wpt);
  // qkv GEMM: writes Q(prescaled),K into qk and V transposed into vtg
  gemm_qkv_kernel<<<dim3(24, 32), 256, 0, stream>>>(xb, wat, qk, vtg, SC);
  // attention (writes yb over wat -- dead after the qkv GEMM)
  attn_kernel<<<dim3(16, 16, 2), 512, 0, stream>>>(qk, vtg, yb);
  // out = y @ w_proj
  gemm_bt64_kernel<float><<<dim3(16, 32), 256, 0, stream>>>(yb, wpt, out, 4096, 1024, 1024);
}